// Round 5
// baseline (208.426 us; speedup 1.0000x reference)
//
#include <hip/hip_runtime.h>

#define B_ 4
#define N_ 2048
#define D_ 512
#define H_ 8
#define S_ (N_ + 1)          // 2049
#define SC 32                // s-rows per chunk
#define NCH 65               // ceil(2049/32)

// workspace layout (float offsets)
#define Q0_OFF   0                                  // unused slack
#define TQ_OFF   1024                               // [H][D] = 4096
#define PW_OFF   8192                               // [NCH][B][H][D] = 1064960
#define PZ_OFF   (PW_OFF + NCH * B_ * H_ * D_)      // [NCH][B][H] = 2080
#define W_OFF    (PZ_OFF + NCH * B_ * H_ + 32)      // [B][H][D] = 16384
#define O0_OFF   (W_OFF + B_ * H_ * D_)             // [B][D]
#define Y_OFF    (O0_OFF + B_ * D_)                 // [B][D]

__device__ __forceinline__ float wave_reduce_sum(float v) {
    #pragma unroll
    for (int off = 32; off > 0; off >>= 1) v += __shfl_down(v, off, 64);
    return v;
}
__device__ __forceinline__ float wave_allreduce_sum(float v) {
    #pragma unroll
    for (int off = 1; off < 64; off <<= 1) v += __shfl_xor(v, off, 64);
    return v;
}

// ---- K1: per head h: q0_h = (Wq x ct + bq)[h*64..] (redundant per block),
// then tq[h,j] = sum_d q0_h[d] * Wk[h*64+d, j].  grid(H,2) x 256
__global__ void tq_kernel(const float* __restrict__ ct,
                          const float* __restrict__ Wq, const float* __restrict__ bq,
                          const float* __restrict__ Wk, float* __restrict__ ws) {
    int h = blockIdx.x, jc = blockIdx.y;
    int tid = threadIdx.x, wv = tid >> 6, lane = tid & 63;
    __shared__ float ct_sh[D_];
    __shared__ float q0_sh[64];
    ct_sh[tid] = ct[tid];
    ct_sh[tid + 256] = ct[tid + 256];
    __syncthreads();
    const float4* c4 = (const float4*)ct_sh;
    float4 ca = c4[lane * 2], cb = c4[lane * 2 + 1];
    #pragma unroll 1
    for (int rr = 0; rr < 16; ++rr) {
        int rl = wv * 16 + rr;
        int r = h * 64 + rl;
        const float4* row = (const float4*)(Wq + (size_t)r * D_);
        float4 a = row[lane * 2], b = row[lane * 2 + 1];
        float acc = a.x*ca.x + a.y*ca.y + a.z*ca.z + a.w*ca.w
                  + b.x*cb.x + b.y*cb.y + b.z*cb.z + b.w*cb.w;
        acc = wave_reduce_sum(acc);
        if (lane == 0) q0_sh[rl] = acc + bq[r];
    }
    __syncthreads();
    int j = jc * 256 + tid;
    float acc = 0.f;
    #pragma unroll 4
    for (int d2 = 0; d2 < 64; ++d2)
        acc += q0_sh[d2] * Wk[(size_t)(h * 64 + d2) * D_ + j];
    ws[TQ_OFF + h * D_ + j] = acc;
}

// ---- K2 (fused attn+wsum): stage 32 x-rows in LDS once; compute 8 head scores
// per row (tq in regs, no max-subtraction: |sc|<<1, masked -> 0); then weighted
// sums from the same LDS copy. One nf pass. grid(NCH, B) x 512.
__global__ void __launch_bounds__(512, 1)
attn_wsum_kernel(const float* __restrict__ nf, const float* __restrict__ ct,
                 const float* __restrict__ masks, float* __restrict__ ws) {
    int chunk = blockIdx.x, b = blockIdx.y;
    int tid = threadIdx.x, wv = tid >> 6, lane = tid & 63;
    __shared__ float xs[SC][D_];        // 64 KB
    __shared__ float sa[H_][SC];        // 1 KB
    int s0 = chunk * SC;
    // phase 0: stage chunk rows (coalesced), zero sa
    float4* xs4 = (float4*)xs;
    #pragma unroll
    for (int i = 0; i < 8; ++i) {
        int f4idx = i * 512 + tid;          // < 4096
        int row = f4idx >> 7, col = f4idx & 127;
        int s = s0 + row;
        if (s < S_) {
            const float4* src = (s == 0) ? (const float4*)ct
                                         : (const float4*)(nf + ((size_t)b * N_ + (s - 1)) * D_);
            xs4[f4idx] = src[col];
        }
    }
    if (tid < H_ * SC) sa[tid >> 5][tid & 31] = 0.f;
    __syncthreads();
    // phase 1: wave wv handles rows wv*4 .. wv*4+3
    {
        const float4* t4 = (const float4*)(ws + TQ_OFF);
        float4 tqa[H_], tqb[H_];
        #pragma unroll
        for (int h = 0; h < H_; ++h) {
            tqa[h] = t4[h * 128 + lane];
            tqb[h] = t4[h * 128 + 64 + lane];
        }
        #pragma unroll
        for (int k = 0; k < 4; ++k) {
            int row = wv * 4 + k;
            int s = s0 + row;
            if (s >= S_) break;
            const float4* x4 = (const float4*)xs[row];
            float4 xa = x4[lane], xb = x4[64 + lane];
            float gate = 1.0f;
            if (s > 0) gate = (masks[b * N_ + s - 1] != 0.0f) ? 1.0f : 0.0f;
            float p[H_];
            #pragma unroll
            for (int h = 0; h < H_; ++h) {
                p[h] = tqa[h].x*xa.x + tqa[h].y*xa.y + tqa[h].z*xa.z + tqa[h].w*xa.w
                     + tqb[h].x*xb.x + tqb[h].y*xb.y + tqb[h].z*xb.z + tqb[h].w*xb.w;
                p[h] = wave_allreduce_sum(p[h]);
            }
            if (lane == 0) {
                #pragma unroll
                for (int h = 0; h < H_; ++h)
                    sa[h][row] = gate * __expf(p[h] * 0.125f);
            }
        }
    }
    __syncthreads();
    // phase 2: thread owns scalar j = tid; accumulate 8 head sums from LDS
    float acc[H_];
    #pragma unroll
    for (int h = 0; h < H_; ++h) acc[h] = 0.f;
    int smax = min(SC, S_ - s0);
    for (int ss = 0; ss < smax; ++ss) {
        float xv = xs[ss][tid];
        #pragma unroll
        for (int h = 0; h < H_; ++h) acc[h] += sa[h][ss] * xv;
    }
    size_t base = ((size_t)chunk * B_ + b) * H_;
    #pragma unroll
    for (int h = 0; h < H_; ++h)
        ws[PW_OFF + (base + h) * D_ + tid] = acc[h];
    if (tid < H_) {
        float z = 0.f;
        #pragma unroll 8
        for (int ss = 0; ss < SC; ++ss) z += sa[tid][ss];
        ws[PZ_OFF + base + tid] = z;
    }
}

// ---- K3: w[b,h,j] = (sum_c pw) / (sum_c pz).  grid(B*H, 4) x 128
__global__ void reduce_w_kernel(float* __restrict__ ws) {
    int bh = blockIdx.x;
    int j = blockIdx.y * 128 + threadIdx.x;
    float z = 0.f;
    #pragma unroll 5
    for (int c = 0; c < NCH; ++c) z += ws[PZ_OFF + (size_t)(c * B_ * H_) + bh];
    float acc = 0.f;
    #pragma unroll 5
    for (int c = 0; c < NCH; ++c)
        acc += ws[PW_OFF + ((size_t)(c * B_ * H_) + bh) * D_ + j];
    ws[W_OFF + (size_t)bh * D_ + j] = acc / z;
}

// ---- K4: o0[b,r] = Wv[r,:] . w[b, r/64, :] + bv[r]   grid(B,128) x 256
__global__ void wv_kernel(const float* __restrict__ Wv, const float* __restrict__ bv,
                          float* __restrict__ ws) {
    int b = blockIdx.x;
    int wv = threadIdx.x >> 6, lane = threadIdx.x & 63;
    int r = blockIdx.y * 4 + wv;
    const float4* wrow = (const float4*)(ws + W_OFF + (size_t)b * H_ * D_ + (size_t)(r >> 6) * D_);
    float4 wa = wrow[lane * 2], wb = wrow[lane * 2 + 1];
    const float4* row = (const float4*)(Wv + (size_t)r * D_);
    float4 a = row[lane * 2], c = row[lane * 2 + 1];
    float acc = a.x*wa.x + a.y*wa.y + a.z*wa.z + a.w*wa.w
              + c.x*wb.x + c.y*wb.y + c.z*wb.z + c.w*wb.w;
    acc = wave_reduce_sum(acc);
    if (lane == 0) ws[O0_OFF + b * D_ + r] = acc + bv[r];
}

// ---- K5: y[b,r] = Wo[r,:] . o0[b,:] + bo[r] + ct[r]   grid(B,128) x 256
__global__ void wo_kernel(const float* __restrict__ Wo, const float* __restrict__ bo,
                          const float* __restrict__ ct, float* __restrict__ ws) {
    int b = blockIdx.x;
    int wv = threadIdx.x >> 6, lane = threadIdx.x & 63;
    int r = blockIdx.y * 4 + wv;
    const float4* ov = (const float4*)(ws + O0_OFF + (size_t)b * D_);
    float4 oa = ov[lane * 2], ob = ov[lane * 2 + 1];
    const float4* row = (const float4*)(Wo + (size_t)r * D_);
    float4 a = row[lane * 2], c = row[lane * 2 + 1];
    float acc = a.x*oa.x + a.y*oa.y + a.z*oa.z + a.w*oa.w
              + c.x*ob.x + c.y*ob.y + c.z*ob.z + c.w*ob.w;
    acc = wave_reduce_sum(acc);
    if (lane == 0) ws[Y_OFF + b * D_ + r] = acc + bo[r] + ct[r];
}

// ---- K6: layernorm over D per batch   grid(B) x 512
__global__ void ln_kernel(const float* __restrict__ gamma, const float* __restrict__ beta,
                          const float* __restrict__ ws, float* __restrict__ out) {
    int b = blockIdx.x;
    int tid = threadIdx.x, wv = tid >> 6, lane = tid & 63;
    float v = ws[Y_OFF + b * D_ + tid];
    float s1 = v, s2 = v * v;
    #pragma unroll
    for (int off = 32; off > 0; off >>= 1) {
        s1 += __shfl_down(s1, off, 64);
        s2 += __shfl_down(s2, off, 64);
    }
    __shared__ float r1[8], r2[8];
    if (lane == 0) { r1[wv] = s1; r2[wv] = s2; }
    __syncthreads();
    if (tid == 0) {
        float a = 0.f, c = 0.f;
        for (int i = 0; i < 8; ++i) { a += r1[i]; c += r2[i]; }
        r1[0] = a; r2[0] = c;
    }
    __syncthreads();
    float mean = r1[0] * (1.0f / D_);
    float var  = r2[0] * (1.0f / D_) - mean * mean;
    float rinv = rsqrtf(var + 1e-5f);
    out[b * D_ + tid] = (v - mean) * rinv * gamma[tid] + beta[tid];
}

extern "C" void kernel_launch(void* const* d_in, const int* in_sizes, int n_in,
                              void* d_out, int out_size, void* d_ws, size_t ws_size,
                              hipStream_t stream) {
    const float* nf    = (const float*)d_in[0];   // node_feat [B,N,D]
    // d_in[1] edge_weights, d_in[2] adj_matrix: not needed for CLS-row output
    const float* masks = (const float*)d_in[3];   // [B,N]
    const float* ct    = (const float*)d_in[4];   // [D]
    const float* Wq    = (const float*)d_in[5];
    const float* bq    = (const float*)d_in[6];
    const float* Wk    = (const float*)d_in[7];
    // d_in[8] bk dropped (softmax shift-invariance)
    const float* Wv    = (const float*)d_in[9];
    const float* bv    = (const float*)d_in[10];
    const float* Wo    = (const float*)d_in[11];
    const float* bo    = (const float*)d_in[12];
    const float* gamma = (const float*)d_in[13];
    const float* beta  = (const float*)d_in[14];
    float* ws  = (float*)d_ws;
    float* out = (float*)d_out;

    hipLaunchKernelGGL(tq_kernel, dim3(H_, 2), dim3(256), 0, stream, ct, Wq, bq, Wk, ws);
    hipLaunchKernelGGL(attn_wsum_kernel, dim3(NCH, B_), dim3(512), 0, stream, nf, ct, masks, ws);
    hipLaunchKernelGGL(reduce_w_kernel, dim3(B_ * H_, 4), dim3(128), 0, stream, ws);
    hipLaunchKernelGGL(wv_kernel, dim3(B_, 128), dim3(256), 0, stream, Wv, bv, ws);
    hipLaunchKernelGGL(wo_kernel, dim3(B_, 128), dim3(256), 0, stream, Wo, bo, ct, ws);
    hipLaunchKernelGGL(ln_kernel, dim3(B_), dim3(512), 0, stream, gamma, beta, ws, out);
}

// Round 6
// 204.743 us; speedup vs baseline: 1.0180x; 1.0180x over previous
//
#include <hip/hip_runtime.h>

#define B_ 4
#define N_ 2048
#define D_ 512
#define H_ 8
#define S_ (N_ + 1)          // 2049
#define SC 32                // s-rows per wsum chunk
#define NCH 65               // ceil(2049/32)

// workspace layout (float offsets)
#define TQ_OFF   1024                               // [H][D] = 4096
#define ATTN_OFF 8192                               // [B*H][S] = 65568
#define PW_OFF   81920                              // [NCH][B][H][D] = 1064960
#define PZ_OFF   (PW_OFF + NCH * B_ * H_ * D_)      // [NCH][B][H] = 2080
#define W_OFF    (PZ_OFF + NCH * B_ * H_ + 32)      // [B][H][D] = 16384
#define O0_OFF   (W_OFF + B_ * H_ * D_)             // [B][D]
#define Y_OFF    (O0_OFF + B_ * D_)                 // [B][D]

__device__ __forceinline__ float wave_reduce_sum(float v) {
    #pragma unroll
    for (int off = 32; off > 0; off >>= 1) v += __shfl_down(v, off, 64);
    return v;
}
__device__ __forceinline__ float wave_allreduce_sum(float v) {
    #pragma unroll
    for (int off = 1; off < 64; off <<= 1) v += __shfl_xor(v, off, 64);
    return v;
}

// ---- K1: per head h: q0_h = (Wq x ct + bq)[h*64..] (redundant per block),
// then tq[h,j] = sum_d q0_h[d] * Wk[h*64+d, j].  grid(H,2) x 256
__global__ void tq_kernel(const float* __restrict__ ct,
                          const float* __restrict__ Wq, const float* __restrict__ bq,
                          const float* __restrict__ Wk, float* __restrict__ ws) {
    int h = blockIdx.x, jc = blockIdx.y;
    int tid = threadIdx.x, wv = tid >> 6, lane = tid & 63;
    __shared__ float ct_sh[D_];
    __shared__ float q0_sh[64];
    ct_sh[tid] = ct[tid];
    ct_sh[tid + 256] = ct[tid + 256];
    __syncthreads();
    const float4* c4 = (const float4*)ct_sh;
    float4 ca = c4[lane * 2], cb = c4[lane * 2 + 1];
    #pragma unroll 1
    for (int rr = 0; rr < 16; ++rr) {
        int rl = wv * 16 + rr;
        int r = h * 64 + rl;
        const float4* row = (const float4*)(Wq + (size_t)r * D_);
        float4 a = row[lane * 2], b = row[lane * 2 + 1];
        float acc = a.x*ca.x + a.y*ca.y + a.z*ca.z + a.w*ca.w
                  + b.x*cb.x + b.y*cb.y + b.z*cb.z + b.w*cb.w;
        acc = wave_reduce_sum(acc);
        if (lane == 0) q0_sh[rl] = acc + bq[r];
    }
    __syncthreads();
    int j = jc * 256 + tid;
    float acc = 0.f;
    #pragma unroll 4
    for (int d2 = 0; d2 < 64; ++d2)
        acc += q0_sh[d2] * Wk[(size_t)(h * 64 + d2) * D_ + j];
    ws[TQ_OFF + h * D_ + j] = acc;
}

// ---- K2: attn[b,h,s] = gate * exp((tq[h].x_s)/8).  grid(257,B) x 512, one s per wave.
// (no max-subtraction: |sc| << 1 here; masked entries -> 0, matching exp(-1e9) underflow)
__global__ void __launch_bounds__(512)
scores_kernel(const float* __restrict__ nf, const float* __restrict__ ct,
              const float* __restrict__ masks, float* __restrict__ ws) {
    int b = blockIdx.y;
    int wv = threadIdx.x >> 6, lane = threadIdx.x & 63;
    int s = blockIdx.x * 8 + wv;
    if (s >= S_) return;
    const float* xrow = (s == 0) ? ct : (nf + ((size_t)b * N_ + (s - 1)) * D_);
    const float4* x4 = (const float4*)xrow;
    float4 xa = x4[lane];        // j = 4*lane
    float4 xb = x4[64 + lane];   // j = 256 + 4*lane
    float gate = 1.0f;
    if (s > 0) gate = (masks[b * N_ + s - 1] != 0.0f) ? 1.0f : 0.0f;
    const float4* t4 = (const float4*)(ws + TQ_OFF);
    float p[H_];
    #pragma unroll
    for (int h = 0; h < H_; ++h) {
        float4 ta = t4[h * 128 + lane], tb = t4[h * 128 + 64 + lane];
        p[h] = ta.x*xa.x + ta.y*xa.y + ta.z*xa.z + ta.w*xa.w
             + tb.x*xb.x + tb.y*xb.y + tb.z*xb.z + tb.w*xb.w;
        p[h] = wave_allreduce_sum(p[h]);
    }
    if (lane == 0) {
        #pragma unroll
        for (int h = 0; h < H_; ++h)
            ws[ATTN_OFF + (size_t)(b * H_ + h) * S_ + s] = gate * __expf(p[h] * 0.125f);
    }
}

// ---- K3: pw[c][b][h][j] = sum_{s in chunk c} attn*x[j]; pz[c][b][h] = sum attn.
// grid(NCH, B) x 512 — thread owns one scalar j; attn chunk broadcast from LDS.
__global__ void __launch_bounds__(512)
wsum_kernel(const float* __restrict__ nf, const float* __restrict__ ct,
            float* __restrict__ ws) {
    int chunk = blockIdx.x, b = blockIdx.y;
    int tid = threadIdx.x;   // = j
    __shared__ float sa[H_][SC];
    int s0 = chunk * SC;
    if (tid < H_ * SC) {
        int h = tid >> 5, ss = tid & 31;
        int s = s0 + ss;
        sa[h][ss] = (s < S_) ? ws[ATTN_OFF + (size_t)(b * H_ + h) * S_ + s] : 0.f;
    }
    __syncthreads();
    float acc[H_];
    #pragma unroll
    for (int h = 0; h < H_; ++h) acc[h] = 0.f;
    int smax = min(SC, S_ - s0);
    for (int ss = 0; ss < smax; ++ss) {
        int s = s0 + ss;
        const float* xrow = (s == 0) ? ct : (nf + ((size_t)b * N_ + (s - 1)) * D_);
        float xv = xrow[tid];
        #pragma unroll
        for (int h = 0; h < H_; ++h) acc[h] += sa[h][ss] * xv;
    }
    size_t base = ((size_t)chunk * B_ + b) * H_;
    #pragma unroll
    for (int h = 0; h < H_; ++h)
        ws[PW_OFF + (base + h) * D_ + tid] = acc[h];
    if (tid < H_) {
        float z = 0.f;
        #pragma unroll 8
        for (int ss = 0; ss < SC; ++ss) z += sa[tid][ss];
        ws[PZ_OFF + base + tid] = z;
    }
}

// ---- K4: w[b,h,j] = (sum_c pw) / (sum_c pz).  grid(B*H, 4) x 128
__global__ void reduce_w_kernel(float* __restrict__ ws) {
    int bh = blockIdx.x;
    int j = blockIdx.y * 128 + threadIdx.x;
    float z = 0.f;
    #pragma unroll 5
    for (int c = 0; c < NCH; ++c) z += ws[PZ_OFF + (size_t)(c * B_ * H_) + bh];
    float acc = 0.f;
    #pragma unroll 5
    for (int c = 0; c < NCH; ++c)
        acc += ws[PW_OFF + ((size_t)(c * B_ * H_) + bh) * D_ + j];
    ws[W_OFF + (size_t)bh * D_ + j] = acc / z;
}

// ---- K5: o0[b,r] = Wv[r,:] . w[b, r/64, :] + bv[r]   grid(B,128) x 256
__global__ void wv_kernel(const float* __restrict__ Wv, const float* __restrict__ bv,
                          float* __restrict__ ws) {
    int b = blockIdx.x;
    int wv = threadIdx.x >> 6, lane = threadIdx.x & 63;
    int r = blockIdx.y * 4 + wv;
    const float4* wrow = (const float4*)(ws + W_OFF + (size_t)b * H_ * D_ + (size_t)(r >> 6) * D_);
    float4 wa = wrow[lane * 2], wb = wrow[lane * 2 + 1];
    const float4* row = (const float4*)(Wv + (size_t)r * D_);
    float4 a = row[lane * 2], c = row[lane * 2 + 1];
    float acc = a.x*wa.x + a.y*wa.y + a.z*wa.z + a.w*wa.w
              + c.x*wb.x + c.y*wb.y + c.z*wb.z + c.w*wb.w;
    acc = wave_reduce_sum(acc);
    if (lane == 0) ws[O0_OFF + b * D_ + r] = acc + bv[r];
}

// ---- K6: y[b,r] = Wo[r,:] . o0[b,:] + bo[r] + ct[r]   grid(B,128) x 256
__global__ void wo_kernel(const float* __restrict__ Wo, const float* __restrict__ bo,
                          const float* __restrict__ ct, float* __restrict__ ws) {
    int b = blockIdx.x;
    int wv = threadIdx.x >> 6, lane = threadIdx.x & 63;
    int r = blockIdx.y * 4 + wv;
    const float4* ov = (const float4*)(ws + O0_OFF + (size_t)b * D_);
    float4 oa = ov[lane * 2], ob = ov[lane * 2 + 1];
    const float4* row = (const float4*)(Wo + (size_t)r * D_);
    float4 a = row[lane * 2], c = row[lane * 2 + 1];
    float acc = a.x*oa.x + a.y*oa.y + a.z*oa.z + a.w*oa.w
              + c.x*ob.x + c.y*ob.y + c.z*ob.z + c.w*ob.w;
    acc = wave_reduce_sum(acc);
    if (lane == 0) ws[Y_OFF + b * D_ + r] = acc + bo[r] + ct[r];
}

// ---- K7: layernorm over D per batch   grid(B) x 512
__global__ void ln_kernel(const float* __restrict__ gamma, const float* __restrict__ beta,
                          const float* __restrict__ ws, float* __restrict__ out) {
    int b = blockIdx.x;
    int tid = threadIdx.x, wv = tid >> 6, lane = tid & 63;
    float v = ws[Y_OFF + b * D_ + tid];
    float s1 = v, s2 = v * v;
    #pragma unroll
    for (int off = 32; off > 0; off >>= 1) {
        s1 += __shfl_down(s1, off, 64);
        s2 += __shfl_down(s2, off, 64);
    }
    __shared__ float r1[8], r2[8];
    if (lane == 0) { r1[wv] = s1; r2[wv] = s2; }
    __syncthreads();
    if (tid == 0) {
        float a = 0.f, c = 0.f;
        for (int i = 0; i < 8; ++i) { a += r1[i]; c += r2[i]; }
        r1[0] = a; r2[0] = c;
    }
    __syncthreads();
    float mean = r1[0] * (1.0f / D_);
    float var  = r2[0] * (1.0f / D_) - mean * mean;
    float rinv = rsqrtf(var + 1e-5f);
    out[b * D_ + tid] = (v - mean) * rinv * gamma[tid] + beta[tid];
}

extern "C" void kernel_launch(void* const* d_in, const int* in_sizes, int n_in,
                              void* d_out, int out_size, void* d_ws, size_t ws_size,
                              hipStream_t stream) {
    const float* nf    = (const float*)d_in[0];   // node_feat [B,N,D]
    // d_in[1] edge_weights, d_in[2] adj_matrix: not needed for CLS-row output
    const float* masks = (const float*)d_in[3];   // [B,N]
    const float* ct    = (const float*)d_in[4];   // [D]
    const float* Wq    = (const float*)d_in[5];
    const float* bq    = (const float*)d_in[6];
    const float* Wk    = (const float*)d_in[7];
    // d_in[8] bk dropped (softmax shift-invariance)
    const float* Wv    = (const float*)d_in[9];
    const float* bv    = (const float*)d_in[10];
    const float* Wo    = (const float*)d_in[11];
    const float* bo    = (const float*)d_in[12];
    const float* gamma = (const float*)d_in[13];
    const float* beta  = (const float*)d_in[14];
    float* ws  = (float*)d_ws;
    float* out = (float*)d_out;

    hipLaunchKernelGGL(tq_kernel, dim3(H_, 2), dim3(256), 0, stream, ct, Wq, bq, Wk, ws);
    hipLaunchKernelGGL(scores_kernel, dim3(257, B_), dim3(512), 0, stream, nf, ct, masks, ws);
    hipLaunchKernelGGL(wsum_kernel, dim3(NCH, B_), dim3(512), 0, stream, nf, ct, ws);
    hipLaunchKernelGGL(reduce_w_kernel, dim3(B_ * H_, 4), dim3(128), 0, stream, ws);
    hipLaunchKernelGGL(wv_kernel, dim3(B_, 128), dim3(256), 0, stream, Wv, bv, ws);
    hipLaunchKernelGGL(wo_kernel, dim3(B_, 128), dim3(256), 0, stream, Wo, bo, ct, ws);
    hipLaunchKernelGGL(ln_kernel, dim3(B_), dim3(512), 0, stream, gamma, beta, ws, out);
}

// Round 7
// 189.931 us; speedup vs baseline: 1.0974x; 1.0780x over previous
//
#include <hip/hip_runtime.h>

#define B_ 4
#define N_ 2048
#define D_ 512
#define H_ 8
#define S_ (N_ + 1)          // 2049
#define SC 32                // s-rows per wsum chunk
#define NCH 65               // ceil(2049/32)

// workspace layout (float offsets)
#define Q0_OFF   0                                  // [512]
#define TQ_OFF   1024                               // [H][D] = 4096
#define ATTN_OFF 8192                               // [B*H][S] = 65568
#define PW_OFF   81920                              // [NCH][B][H][D] = 1064960
#define PZ_OFF   (PW_OFF + NCH * B_ * H_ * D_)      // [NCH][B][H] = 2080
#define W_OFF    (PZ_OFF + NCH * B_ * H_ + 32)      // [B][H][D] = 16384
#define O0_OFF   (W_OFF + B_ * H_ * D_)             // [B][D]
#define Y_OFF    (O0_OFF + B_ * D_)                 // [B][D]

__device__ __forceinline__ float wave_reduce_sum(float v) {
    #pragma unroll
    for (int off = 32; off > 0; off >>= 1) v += __shfl_down(v, off, 64);
    return v;
}
__device__ __forceinline__ float wave_allreduce_sum(float v) {
    #pragma unroll
    for (int off = 1; off < 64; off <<= 1) v += __shfl_xor(v, off, 64);
    return v;
}

// ---- K1: q0[r] = Wq[r,:].ct + bq[r].  grid(64) x 512 — one wave per row, fully parallel.
// (keep split from tq: merged 16-block serial version measured +14 us in R6)
__global__ void q0_kernel(const float* __restrict__ ct,
                          const float* __restrict__ Wq, const float* __restrict__ bq,
                          float* __restrict__ ws) {
    int wv = threadIdx.x >> 6, lane = threadIdx.x & 63;
    int r = blockIdx.x * 8 + wv;
    const float4* c4 = (const float4*)ct;
    float4 ca = c4[lane * 2], cb = c4[lane * 2 + 1];
    const float4* row = (const float4*)(Wq + (size_t)r * D_);
    float4 a = row[lane * 2], b = row[lane * 2 + 1];
    float acc = a.x*ca.x + a.y*ca.y + a.z*ca.z + a.w*ca.w
              + b.x*cb.x + b.y*cb.y + b.z*cb.z + b.w*cb.w;
    acc = wave_reduce_sum(acc);
    if (lane == 0) ws[Q0_OFF + r] = acc + bq[r];
}

// ---- K2: tq[h,j] = sum_d q0[h*64+d] * Wk[h*64+d, j].  grid(H,4) x 128
__global__ void tq_kernel(const float* __restrict__ Wk, float* __restrict__ ws) {
    int h = blockIdx.x, jc = blockIdx.y;
    int tid = threadIdx.x;
    __shared__ float q0s[64];
    if (tid < 64) q0s[tid] = ws[Q0_OFF + h * 64 + tid];
    __syncthreads();
    int j = jc * 128 + tid;
    float acc = 0.f;
    #pragma unroll 8
    for (int d2 = 0; d2 < 64; ++d2)
        acc += q0s[d2] * Wk[(size_t)(h * 64 + d2) * D_ + j];
    ws[TQ_OFF + h * D_ + j] = acc;
}

// ---- K3: attn[b,h,s] = gate * exp((tq[h].x_s)/8).  grid(257,B) x 512, one s per wave.
// (no max-subtraction: |sc| << 1 here; masked entries -> 0, matching exp(-1e9) underflow)
__global__ void __launch_bounds__(512)
scores_kernel(const float* __restrict__ nf, const float* __restrict__ ct,
              const float* __restrict__ masks, float* __restrict__ ws) {
    int b = blockIdx.y;
    int wv = threadIdx.x >> 6, lane = threadIdx.x & 63;
    int s = blockIdx.x * 8 + wv;
    if (s >= S_) return;
    const float* xrow = (s == 0) ? ct : (nf + ((size_t)b * N_ + (s - 1)) * D_);
    const float4* x4 = (const float4*)xrow;
    float4 xa = x4[lane];        // j = 4*lane
    float4 xb = x4[64 + lane];   // j = 256 + 4*lane
    float gate = 1.0f;
    if (s > 0) gate = (masks[b * N_ + s - 1] != 0.0f) ? 1.0f : 0.0f;
    const float4* t4 = (const float4*)(ws + TQ_OFF);
    float p[H_];
    #pragma unroll
    for (int h = 0; h < H_; ++h) {
        float4 ta = t4[h * 128 + lane], tb = t4[h * 128 + 64 + lane];
        p[h] = ta.x*xa.x + ta.y*xa.y + ta.z*xa.z + ta.w*xa.w
             + tb.x*xb.x + tb.y*xb.y + tb.z*xb.z + tb.w*xb.w;
        p[h] = wave_allreduce_sum(p[h]);
    }
    if (lane == 0) {
        #pragma unroll
        for (int h = 0; h < H_; ++h)
            ws[ATTN_OFF + (size_t)(b * H_ + h) * S_ + s] = gate * __expf(p[h] * 0.125f);
    }
}

// ---- K4: pw[c][b][h][j] = sum_{s in chunk c} attn*x[j]; pz[c][b][h] = sum attn.
// grid(NCH, B) x 512 — thread owns one scalar j; attn chunk broadcast from LDS.
// (second nf pass is L3-resident — measured cheaper than the 64KB-LDS fusion, R5)
__global__ void __launch_bounds__(512)
wsum_kernel(const float* __restrict__ nf, const float* __restrict__ ct,
            float* __restrict__ ws) {
    int chunk = blockIdx.x, b = blockIdx.y;
    int tid = threadIdx.x;   // = j
    __shared__ float sa[H_][SC];
    int s0 = chunk * SC;
    if (tid < H_ * SC) {
        int h = tid >> 5, ss = tid & 31;
        int s = s0 + ss;
        sa[h][ss] = (s < S_) ? ws[ATTN_OFF + (size_t)(b * H_ + h) * S_ + s] : 0.f;
    }
    __syncthreads();
    float acc[H_];
    #pragma unroll
    for (int h = 0; h < H_; ++h) acc[h] = 0.f;
    int smax = min(SC, S_ - s0);
    for (int ss = 0; ss < smax; ++ss) {
        int s = s0 + ss;
        const float* xrow = (s == 0) ? ct : (nf + ((size_t)b * N_ + (s - 1)) * D_);
        float xv = xrow[tid];
        #pragma unroll
        for (int h = 0; h < H_; ++h) acc[h] += sa[h][ss] * xv;
    }
    size_t base = ((size_t)chunk * B_ + b) * H_;
    #pragma unroll
    for (int h = 0; h < H_; ++h)
        ws[PW_OFF + (base + h) * D_ + tid] = acc[h];
    if (tid < H_) {
        float z = 0.f;
        #pragma unroll 8
        for (int ss = 0; ss < SC; ++ss) z += sa[tid][ss];
        ws[PZ_OFF + base + tid] = z;
    }
}

// ---- K5: w[b,h,j] = (sum_c pw) / (sum_c pz).  grid(B*H, 4) x 128
__global__ void reduce_w_kernel(float* __restrict__ ws) {
    int bh = blockIdx.x;                 // b*H + h
    int j = blockIdx.y * 128 + threadIdx.x;
    float z = 0.f;
    #pragma unroll 5
    for (int c = 0; c < NCH; ++c) z += ws[PZ_OFF + (size_t)(c * B_ * H_) + bh];
    float acc = 0.f;
    #pragma unroll 5
    for (int c = 0; c < NCH; ++c)
        acc += ws[PW_OFF + ((size_t)(c * B_ * H_) + bh) * D_ + j];
    ws[W_OFF + (size_t)bh * D_ + j] = acc / z;
}

// ---- K6: o0[b,r] = Wv[r,:] . w[b, r/64, :] + bv[r]   grid(B,128) x 256
__global__ void wv_kernel(const float* __restrict__ Wv, const float* __restrict__ bv,
                          float* __restrict__ ws) {
    int b = blockIdx.x;
    int wv = threadIdx.x >> 6, lane = threadIdx.x & 63;
    int r = blockIdx.y * 4 + wv;
    const float4* wrow = (const float4*)(ws + W_OFF + (size_t)b * H_ * D_ + (size_t)(r >> 6) * D_);
    float4 wa = wrow[lane * 2], wb = wrow[lane * 2 + 1];
    const float4* row = (const float4*)(Wv + (size_t)r * D_);
    float4 a = row[lane * 2], c = row[lane * 2 + 1];
    float acc = a.x*wa.x + a.y*wa.y + a.z*wa.z + a.w*wa.w
              + c.x*wb.x + c.y*wb.y + c.z*wb.z + c.w*wb.w;
    acc = wave_reduce_sum(acc);
    if (lane == 0) ws[O0_OFF + b * D_ + r] = acc + bv[r];
}

// ---- K7: y[b,r] = Wo[r,:] . o0[b,:] + bo[r] + ct[r]   grid(B,128) x 256
__global__ void wo_kernel(const float* __restrict__ Wo, const float* __restrict__ bo,
                          const float* __restrict__ ct, float* __restrict__ ws) {
    int b = blockIdx.x;
    int wv = threadIdx.x >> 6, lane = threadIdx.x & 63;
    int r = blockIdx.y * 4 + wv;
    const float4* ov = (const float4*)(ws + O0_OFF + (size_t)b * D_);
    float4 oa = ov[lane * 2], ob = ov[lane * 2 + 1];
    const float4* row = (const float4*)(Wo + (size_t)r * D_);
    float4 a = row[lane * 2], c = row[lane * 2 + 1];
    float acc = a.x*oa.x + a.y*oa.y + a.z*oa.z + a.w*oa.w
              + c.x*ob.x + c.y*ob.y + c.z*ob.z + c.w*ob.w;
    acc = wave_reduce_sum(acc);
    if (lane == 0) ws[Y_OFF + b * D_ + r] = acc + bo[r] + ct[r];
}

// ---- K8: layernorm over D per batch   grid(B) x 512
__global__ void ln_kernel(const float* __restrict__ gamma, const float* __restrict__ beta,
                          const float* __restrict__ ws, float* __restrict__ out) {
    int b = blockIdx.x;
    int tid = threadIdx.x, wv = tid >> 6, lane = tid & 63;
    float v = ws[Y_OFF + b * D_ + tid];
    float s1 = v, s2 = v * v;
    #pragma unroll
    for (int off = 32; off > 0; off >>= 1) {
        s1 += __shfl_down(s1, off, 64);
        s2 += __shfl_down(s2, off, 64);
    }
    __shared__ float r1[8], r2[8];
    if (lane == 0) { r1[wv] = s1; r2[wv] = s2; }
    __syncthreads();
    if (tid == 0) {
        float a = 0.f, c = 0.f;
        for (int i = 0; i < 8; ++i) { a += r1[i]; c += r2[i]; }
        r1[0] = a; r2[0] = c;
    }
    __syncthreads();
    float mean = r1[0] * (1.0f / D_);
    float var  = r2[0] * (1.0f / D_) - mean * mean;
    float rinv = rsqrtf(var + 1e-5f);
    out[b * D_ + tid] = (v - mean) * rinv * gamma[tid] + beta[tid];
}

extern "C" void kernel_launch(void* const* d_in, const int* in_sizes, int n_in,
                              void* d_out, int out_size, void* d_ws, size_t ws_size,
                              hipStream_t stream) {
    const float* nf    = (const float*)d_in[0];   // node_feat [B,N,D]
    // d_in[1] edge_weights, d_in[2] adj_matrix: not needed for CLS-row output
    const float* masks = (const float*)d_in[3];   // [B,N]
    const float* ct    = (const float*)d_in[4];   // [D]
    const float* Wq    = (const float*)d_in[5];
    const float* bq    = (const float*)d_in[6];
    const float* Wk    = (const float*)d_in[7];
    // d_in[8] bk dropped (softmax shift-invariance)
    const float* Wv    = (const float*)d_in[9];
    const float* bv    = (const float*)d_in[10];
    const float* Wo    = (const float*)d_in[11];
    const float* bo    = (const float*)d_in[12];
    const float* gamma = (const float*)d_in[13];
    const float* beta  = (const float*)d_in[14];
    float* ws  = (float*)d_ws;
    float* out = (float*)d_out;

    hipLaunchKernelGGL(q0_kernel, dim3(64), dim3(512), 0, stream, ct, Wq, bq, ws);
    hipLaunchKernelGGL(tq_kernel, dim3(H_, 4), dim3(128), 0, stream, Wk, ws);
    hipLaunchKernelGGL(scores_kernel, dim3(257, B_), dim3(512), 0, stream, nf, ct, masks, ws);
    hipLaunchKernelGGL(wsum_kernel, dim3(NCH, B_), dim3(512), 0, stream, nf, ct, ws);
    hipLaunchKernelGGL(reduce_w_kernel, dim3(B_ * H_, 4), dim3(128), 0, stream, ws);
    hipLaunchKernelGGL(wv_kernel, dim3(B_, 128), dim3(256), 0, stream, Wv, bv, ws);
    hipLaunchKernelGGL(wo_kernel, dim3(B_, 128), dim3(256), 0, stream, Wo, bo, ct, ws);
    hipLaunchKernelGGL(ln_kernel, dim3(B_), dim3(512), 0, stream, gamma, beta, ws, out);
}